// Round 1
// baseline (480.513 us; speedup 1.0000x reference)
//
#include <hip/hip_runtime.h>

// 14-qubit state-vector sim, one workgroup per batch element, state in LDS.
// Wire w <-> bit (13-w). CNOT rings are GF(2)-linear permutations folded into
// the preceding pass's scatter writes. First Rot layer is applied analytically
// to the (basis-state) embedded input as a product state.

#define NW 14
#define NSTATE (1 << NW)                      // 16384
#define NTHREADS 1024
#define STATE_SLOTS (NSTATE + (NSTATE >> 6))  // +1 float2 pad per 64 amps

__device__ __forceinline__ int SLOT(int i) { return i + (i >> 6); }

__device__ __forceinline__ float2 cmul(float2 a, float2 b) {
    return make_float2(a.x * b.x - a.y * b.y, a.x * b.y + a.y * b.x);
}
__device__ __forceinline__ float2 cadd(float2 a, float2 b) {
    return make_float2(a.x + b.x, a.y + b.y);
}

// Apply 4 Rot gates (bits LO..LO+3) to the whole state, in-place, 16 amps/thread.
template<int LO>
__device__ __forceinline__ void rot_pass(float2* st_, const float2 (*R)[4], int t)
{
    const int lowmask = (1 << LO) - 1;
    const int base = ((t >> LO) << (LO + 4)) | (t & lowmask);
    float2 a[16];
    int idx[16];
#pragma unroll
    for (int k = 0; k < 16; ++k) {
        idx[k] = SLOT(base | (k << LO));
        a[k] = st_[idx[k]];
    }
#pragma unroll
    for (int q = 3; q >= 0; --q) {
        const int w = 13 - LO - q;                 // wire for k-bit q
        const float2 u00 = R[w][0], u01 = R[w][1], u10 = R[w][2], u11 = R[w][3];
        const int sd = 1 << q;
#pragma unroll
        for (int m = 0; m < 16; ++m) {
            if (m & sd) continue;
            float2 a0 = a[m], a1 = a[m | sd];
            a[m]      = cadd(cmul(u00, a0), cmul(u01, a1));
            a[m | sd] = cadd(cmul(u10, a0), cmul(u11, a1));
        }
    }
#pragma unroll
    for (int k = 0; k < 16; ++k) st_[idx[k]] = a[k];
}

// Last pass of a layer: gates on wires 12,13 (bits 1,0), then the CNOT-ring
// permutation folded into the scatter writes: st[f(i)] = new_amp(i).
__device__ __forceinline__ void rot_low_ring(float2* st_, const float2 (*R)[4], int t,
                                             const unsigned* colr, const unsigned* flowr)
{
    const int base = t << 4;
    float2 a[16];
#pragma unroll
    for (int k = 0; k < 16; ++k) a[k] = st_[SLOT(base | k)];
    const float2 A00 = R[12][0], A01 = R[12][1], A10 = R[12][2], A11 = R[12][3];
    const float2 B00 = R[13][0], B01 = R[13][1], B10 = R[13][2], B11 = R[13][3];
#pragma unroll
    for (int j = 0; j < 16; j += 4) {
#pragma unroll
        for (int m = 0; m < 2; ++m) {          // wire 12 on bit 1
            float2 a0 = a[j + m], a1 = a[j + m + 2];
            a[j + m]     = cadd(cmul(A00, a0), cmul(A01, a1));
            a[j + m + 2] = cadd(cmul(A10, a0), cmul(A11, a1));
        }
#pragma unroll
        for (int m = 0; m < 4; m += 2) {       // wire 13 on bit 0
            float2 a0 = a[j + m], a1 = a[j + m + 1];
            a[j + m]     = cadd(cmul(B00, a0), cmul(B01, a1));
            a[j + m + 1] = cadd(cmul(B10, a0), cmul(B11, a1));
        }
    }
    unsigned fb = 0;                            // f(base): XOR of columns, bits 4..13
#pragma unroll
    for (int bit = 4; bit < 14; ++bit)
        if ((t >> (bit - 4)) & 1) fb ^= colr[bit];
    __syncthreads();                            // all reads done before scatter
#pragma unroll
    for (int k = 0; k < 16; ++k) st_[SLOT((int)(fb ^ flowr[k]))] = a[k];
}

__global__ __launch_bounds__(NTHREADS, 1)
void qsim(const float* __restrict__ sb, const float* __restrict__ pr,
          const float* __restrict__ hw, const float* __restrict__ hb,
          float* __restrict__ out)
{
    __shared__ float2 st[STATE_SLOTS];          // 133,120 B
    __shared__ float2 rot[2][NW][4];            // Rot matrices per (layer, wire)
    __shared__ unsigned colm[2][NW];            // ring permutation columns, r=1,2
    __shared__ unsigned flow[2][16];            // f(k) for k<16
    __shared__ float s_hw[NW];
    __shared__ float s_red[NTHREADS / 64];
    __shared__ unsigned s_bmask;

    const int bid = blockIdx.x;
    const int t = threadIdx.x;

    // ---- setup: Rot matrices, ring columns, head weights, basis mask ----
    if (t < 28) {
        int l = t / NW, w = t % NW;
        const float* p = pr + bid * 84 + l * 42 + w * 3;
        float phi = p[0], th = p[1], om = p[2];
        float s, c;  __sincosf(0.5f * th, &s, &c);
        float sa, ca, sd, cd;
        __sincosf(0.5f * (phi + om), &sa, &ca);
        __sincosf(0.5f * (phi - om), &sd, &cd);
        rot[l][w][0] = make_float2(ca * c, -sa * c);   // u00 = e^{-i(phi+om)/2} c
        rot[l][w][1] = make_float2(-cd * s, -sd * s);  // u01 = -e^{+i(phi-om)/2} s
        rot[l][w][2] = make_float2(cd * s, -sd * s);   // u10 = e^{-i(phi-om)/2} s
        rot[l][w][3] = make_float2(ca * c, sa * c);    // u11 = e^{+i(phi+om)/2} c
    }
    if (t >= 64 && t < 92) {                    // columns of ring permutation
        int j = t - 64, ri = j / NW, bb = j % NW;
        unsigned x = 1u << bb;
        for (int w = 0; w < NW; ++w) {          // CNOT(w, (w+r)%14), r = ri+1
            int pc = 13 - w, pt = 13 - ((w + ri + 1) % NW);
            x ^= ((x >> pc) & 1u) << pt;
        }
        colm[ri][bb] = x;
    }
    if (t >= 128 && t < 142) s_hw[t - 128] = hw[t - 128];
    if (t == 192) {                             // basis index from sign bits
        const float* row = sb + (size_t)bid * (NSTATE * 2);
        unsigned m = 0;
        for (int w = 0; w < NW; ++w) m |= (row[w] < 0.0f ? 1u : 0u) << (13 - w);
        s_bmask = m;
    }
    __syncthreads();
    if (t < 32) {                               // f(k) tables for k<16
        int ri = t >> 4, k = t & 15;
        unsigned x = 0;
        for (int bpos = 0; bpos < 4; ++bpos)
            if ((k >> bpos) & 1) x ^= colm[ri][bpos];
        flow[ri][k] = x;
    }
    __syncthreads();

    // ---- init: first Rot layer applied to basis state |bm> = product state,
    //      with the first ring (r=1) folded into the writes ----
    {
        const unsigned bm = s_bmask;
        float2 ph = make_float2(1.f, 0.f);
#pragma unroll
        for (int w = 0; w < 10; ++w) {          // wires 0..9 from t bits
            int v = (t >> (9 - w)) & 1;
            int bw = (bm >> (13 - w)) & 1;
            ph = cmul(ph, rot[0][w][v * 2 + bw]);
        }
        unsigned fb = 0;
#pragma unroll
        for (int bit = 4; bit < 14; ++bit)
            if ((t >> (bit - 4)) & 1) fb ^= colm[0][bit];
#pragma unroll
        for (int k = 0; k < 16; ++k) {          // wires 10..13 from k bits
            float2 pl = rot[0][10][(((k >> 3) & 1) * 2) + ((bm >> 3) & 1)];
            pl = cmul(pl, rot[0][11][(((k >> 2) & 1) * 2) + ((bm >> 2) & 1)]);
            pl = cmul(pl, rot[0][12][(((k >> 1) & 1) * 2) + ((bm >> 1) & 1)]);
            pl = cmul(pl, rot[0][13][((k & 1) * 2) + (bm & 1)]);
            st[SLOT((int)(fb ^ flow[0][k]))] = cmul(ph, pl);
        }
    }
    __syncthreads();

    // ---- remaining 5 Rot layers, each with its trailing ring folded in.
    // Sequence after init+ring1: (l1,r2),(l0,r1),(l1,r2),(l0,r1),(l1,r2) ----
#pragma unroll 1
    for (int rep = 0; rep < 5; ++rep) {
        const int l = (rep & 1) ? 0 : 1;        // ring r = l+1 -> colm[l]/flow[l]
        rot_pass<10>(st, rot[l], t); __syncthreads();   // wires 0..3
        rot_pass<6>(st, rot[l], t);  __syncthreads();   // wires 4..7
        rot_pass<2>(st, rot[l], t);  __syncthreads();   // wires 8..11
        rot_low_ring(st, rot[l], t, colm[l], flow[l]);  // wires 12,13 + ring
        __syncthreads();
    }

    // ---- measurement: out = sum_i |psi_i|^2 * (sum_w hw[w]*(-1)^{bit_w(i)}) + hb ----
    float chi = 0.f;
#pragma unroll
    for (int w = 0; w < 10; ++w)
        chi += ((t >> (9 - w)) & 1) ? -s_hw[w] : s_hw[w];
    float acc = 0.f;
#pragma unroll
    for (int k = 0; k < 16; ++k) {
        float2 v = st[SLOT((t << 4) | k)];
        float cc = chi;
        cc += ((k >> 3) & 1) ? -s_hw[10] : s_hw[10];
        cc += ((k >> 2) & 1) ? -s_hw[11] : s_hw[11];
        cc += ((k >> 1) & 1) ? -s_hw[12] : s_hw[12];
        cc += (k & 1)        ? -s_hw[13] : s_hw[13];
        acc += (v.x * v.x + v.y * v.y) * cc;
    }
    for (int off = 32; off > 0; off >>= 1) acc += __shfl_down(acc, off);
    if ((t & 63) == 0) s_red[t >> 6] = acc;
    __syncthreads();
    if (t == 0) {
        float tot = 0.f;
#pragma unroll
        for (int i = 0; i < NTHREADS / 64; ++i) tot += s_red[i];
        out[bid] = tot + hb[0];
    }
}

extern "C" void kernel_launch(void* const* d_in, const int* in_sizes, int n_in,
                              void* d_out, int out_size, void* d_ws, size_t ws_size,
                              hipStream_t stream)
{
    const float* sb = (const float*)d_in[0];   // state_batch (B, 2^14, 2) f32
    const float* pr = (const float*)d_in[1];   // params (B, 84) f32
    const float* hw = (const float*)d_in[2];   // head_w (1, 14) f32
    const float* hb = (const float*)d_in[3];   // head_b (1,) f32
    float* out = (float*)d_out;                // (B,) f32
    const int B = in_sizes[1] / 84;            // 512
    qsim<<<B, NTHREADS, 0, stream>>>(sb, pr, hw, hb, out);
}

// Round 2
// 285.700 us; speedup vs baseline: 1.6819x; 1.6819x over previous
//
#include <hip/hip_runtime.h>

// 14-qubit state-vector sim, one workgroup per batch element, state in LDS.
// Wire w <-> bit (13-w). CNOT rings are GF(2)-linear permutations folded into
// the preceding pass's scatter writes. First Rot layer is applied analytically
// to the (basis-state) embedded input as a product state.
// R2: fully scalarized amplitudes (no private arrays -> no scratch/HBM spill),
//     pad 2 float2 per 64 amps (keeps 16B alignment for float4 LDS loads).

#define NW 14
#define NSTATE (1 << NW)                      // 16384
#define NTHREADS 1024
#define STATE_SLOTS (NSTATE + ((NSTATE >> 6) << 1))  // +2 float2 pad per 64 amps

__device__ __forceinline__ int SLOT(int i) { return i + ((i >> 6) << 1); }

__device__ __forceinline__ float2 cmul(float2 a, float2 b) {
    return make_float2(a.x * b.x - a.y * b.y, a.x * b.y + a.y * b.x);
}
__device__ __forceinline__ float2 cadd(float2 a, float2 b) {
    return make_float2(a.x + b.x, a.y + b.y);
}

#define BF(X, Y) { float2 t0 = X, t1 = Y;            \
    X = cadd(cmul(u00, t0), cmul(u01, t1));          \
    Y = cadd(cmul(u10, t0), cmul(u11, t1)); }

// Apply 4 Rot gates (k-bits 3..0 = wires 13-LO-3 .. 13-LO) to 16 amps/thread.
template<int LO>
__device__ __forceinline__ void rot_pass(float2* st_, const float2 (*R)[4], int t)
{
    const int lowmask = (1 << LO) - 1;
    const int base = ((t >> LO) << (LO + 4)) | (t & lowmask);
#define STE(k) st_[SLOT(base | ((k) << LO))]
    float2 a0 = STE(0),  a1 = STE(1),  a2 = STE(2),  a3 = STE(3),
           a4 = STE(4),  a5 = STE(5),  a6 = STE(6),  a7 = STE(7),
           a8 = STE(8),  a9 = STE(9),  a10 = STE(10), a11 = STE(11),
           a12 = STE(12), a13 = STE(13), a14 = STE(14), a15 = STE(15);
    {   // wire 10-LO on k-bit 3
        const float2 u00 = R[10 - LO][0], u01 = R[10 - LO][1],
                     u10 = R[10 - LO][2], u11 = R[10 - LO][3];
        BF(a0, a8)  BF(a1, a9)  BF(a2, a10) BF(a3, a11)
        BF(a4, a12) BF(a5, a13) BF(a6, a14) BF(a7, a15)
    }
    {   // wire 11-LO on k-bit 2
        const float2 u00 = R[11 - LO][0], u01 = R[11 - LO][1],
                     u10 = R[11 - LO][2], u11 = R[11 - LO][3];
        BF(a0, a4)  BF(a1, a5)  BF(a2, a6)  BF(a3, a7)
        BF(a8, a12) BF(a9, a13) BF(a10, a14) BF(a11, a15)
    }
    {   // wire 12-LO on k-bit 1
        const float2 u00 = R[12 - LO][0], u01 = R[12 - LO][1],
                     u10 = R[12 - LO][2], u11 = R[12 - LO][3];
        BF(a0, a2)  BF(a1, a3)  BF(a4, a6)  BF(a5, a7)
        BF(a8, a10) BF(a9, a11) BF(a12, a14) BF(a13, a15)
    }
    {   // wire 13-LO on k-bit 0
        const float2 u00 = R[13 - LO][0], u01 = R[13 - LO][1],
                     u10 = R[13 - LO][2], u11 = R[13 - LO][3];
        BF(a0, a1)  BF(a2, a3)  BF(a4, a5)  BF(a6, a7)
        BF(a8, a9)  BF(a10, a11) BF(a12, a13) BF(a14, a15)
    }
    STE(0) = a0;   STE(1) = a1;   STE(2) = a2;   STE(3) = a3;
    STE(4) = a4;   STE(5) = a5;   STE(6) = a6;   STE(7) = a7;
    STE(8) = a8;   STE(9) = a9;   STE(10) = a10; STE(11) = a11;
    STE(12) = a12; STE(13) = a13; STE(14) = a14; STE(15) = a15;
#undef STE
}

// Last pass of a layer: gates on wires 12,13 (bits 1,0), then the CNOT-ring
// permutation folded into the scatter writes: st[f(i)] = new_amp(i).
__device__ __forceinline__ void rot_low_ring(float2* st_, const float2 (*R)[4], int t,
                                             const unsigned* colr, const unsigned* flowr)
{
    const int sb0 = SLOT(t << 4);               // 16B-aligned (pad is 2 float2)
    const float4* lp = (const float4*)(st_ + sb0);
    float4 v0 = lp[0], v1 = lp[1], v2 = lp[2], v3 = lp[3],
           v4 = lp[4], v5 = lp[5], v6 = lp[6], v7 = lp[7];
    float2 a0  = make_float2(v0.x, v0.y), a1  = make_float2(v0.z, v0.w),
           a2  = make_float2(v1.x, v1.y), a3  = make_float2(v1.z, v1.w),
           a4  = make_float2(v2.x, v2.y), a5  = make_float2(v2.z, v2.w),
           a6  = make_float2(v3.x, v3.y), a7  = make_float2(v3.z, v3.w),
           a8  = make_float2(v4.x, v4.y), a9  = make_float2(v4.z, v4.w),
           a10 = make_float2(v5.x, v5.y), a11 = make_float2(v5.z, v5.w),
           a12 = make_float2(v6.x, v6.y), a13 = make_float2(v6.z, v6.w),
           a14 = make_float2(v7.x, v7.y), a15 = make_float2(v7.z, v7.w);
    {   // wire 12 on bit 1
        const float2 u00 = R[12][0], u01 = R[12][1], u10 = R[12][2], u11 = R[12][3];
        BF(a0, a2)  BF(a1, a3)  BF(a4, a6)  BF(a5, a7)
        BF(a8, a10) BF(a9, a11) BF(a12, a14) BF(a13, a15)
    }
    {   // wire 13 on bit 0
        const float2 u00 = R[13][0], u01 = R[13][1], u10 = R[13][2], u11 = R[13][3];
        BF(a0, a1)  BF(a2, a3)  BF(a4, a5)  BF(a6, a7)
        BF(a8, a9)  BF(a10, a11) BF(a12, a13) BF(a14, a15)
    }
    unsigned fb = 0;                            // f(base): XOR of columns, bits 4..13
#pragma unroll
    for (int bit = 4; bit < 14; ++bit)
        if ((t >> (bit - 4)) & 1) fb ^= colr[bit];
    __syncthreads();                            // all reads done before scatter
    st_[SLOT((int)(fb ^ flowr[0]))]  = a0;
    st_[SLOT((int)(fb ^ flowr[1]))]  = a1;
    st_[SLOT((int)(fb ^ flowr[2]))]  = a2;
    st_[SLOT((int)(fb ^ flowr[3]))]  = a3;
    st_[SLOT((int)(fb ^ flowr[4]))]  = a4;
    st_[SLOT((int)(fb ^ flowr[5]))]  = a5;
    st_[SLOT((int)(fb ^ flowr[6]))]  = a6;
    st_[SLOT((int)(fb ^ flowr[7]))]  = a7;
    st_[SLOT((int)(fb ^ flowr[8]))]  = a8;
    st_[SLOT((int)(fb ^ flowr[9]))]  = a9;
    st_[SLOT((int)(fb ^ flowr[10]))] = a10;
    st_[SLOT((int)(fb ^ flowr[11]))] = a11;
    st_[SLOT((int)(fb ^ flowr[12]))] = a12;
    st_[SLOT((int)(fb ^ flowr[13]))] = a13;
    st_[SLOT((int)(fb ^ flowr[14]))] = a14;
    st_[SLOT((int)(fb ^ flowr[15]))] = a15;
}

__global__ __launch_bounds__(NTHREADS, 4)
void qsim(const float* __restrict__ sb, const float* __restrict__ pr,
          const float* __restrict__ hw, const float* __restrict__ hb,
          float* __restrict__ out)
{
    __shared__ __align__(16) float2 st[STATE_SLOTS];   // 135,168 B
    __shared__ float2 rot[2][NW][4];            // Rot matrices per (layer, wire)
    __shared__ unsigned colm[2][NW];            // ring permutation columns, r=1,2
    __shared__ unsigned flow[2][16];            // f(k) for k<16
    __shared__ float s_hw[NW];
    __shared__ float s_red[NTHREADS / 64];
    __shared__ unsigned s_bmask;

    const int bid = blockIdx.x;
    const int t = threadIdx.x;

    // ---- setup: Rot matrices, ring columns, head weights, basis mask ----
    if (t < 28) {
        int l = t / NW, w = t % NW;
        const float* p = pr + bid * 84 + l * 42 + w * 3;
        float phi = p[0], th = p[1], om = p[2];
        float s, c;  __sincosf(0.5f * th, &s, &c);
        float sa, ca, sd, cd;
        __sincosf(0.5f * (phi + om), &sa, &ca);
        __sincosf(0.5f * (phi - om), &sd, &cd);
        rot[l][w][0] = make_float2(ca * c, -sa * c);   // u00 = e^{-i(phi+om)/2} c
        rot[l][w][1] = make_float2(-cd * s, -sd * s);  // u01 = -e^{+i(phi-om)/2} s
        rot[l][w][2] = make_float2(cd * s, -sd * s);   // u10 = e^{-i(phi-om)/2} s
        rot[l][w][3] = make_float2(ca * c, sa * c);    // u11 = e^{+i(phi+om)/2} c
    }
    if (t >= 64 && t < 92) {                    // columns of ring permutation
        int j = t - 64, ri = j / NW, bb = j % NW;
        unsigned x = 1u << bb;
        for (int w = 0; w < NW; ++w) {          // CNOT(w, (w+r)%14), r = ri+1
            int pc = 13 - w, pt = 13 - ((w + ri + 1) % NW);
            x ^= ((x >> pc) & 1u) << pt;
        }
        colm[ri][bb] = x;
    }
    if (t >= 128 && t < 142) s_hw[t - 128] = hw[t - 128];
    if (t == 192) {                             // basis index from sign bits
        const float* row = sb + (size_t)bid * (NSTATE * 2);
        unsigned m = 0;
        for (int w = 0; w < NW; ++w) m |= (row[w] < 0.0f ? 1u : 0u) << (13 - w);
        s_bmask = m;
    }
    __syncthreads();
    if (t < 32) {                               // f(k) tables for k<16
        int ri = t >> 4, k = t & 15;
        unsigned x = 0;
        for (int bpos = 0; bpos < 4; ++bpos)
            if ((k >> bpos) & 1) x ^= colm[ri][bpos];
        flow[ri][k] = x;
    }
    __syncthreads();

    // ---- init: first Rot layer applied to basis state |bm> = product state,
    //      with the first ring (r=1) folded into the writes ----
    {
        const unsigned bm = s_bmask;
        float2 ph = make_float2(1.f, 0.f);
#pragma unroll
        for (int w = 0; w < 10; ++w) {          // wires 0..9 from t bits
            int v = (t >> (9 - w)) & 1;
            int bw = (bm >> (13 - w)) & 1;
            ph = cmul(ph, rot[0][w][v * 2 + bw]);
        }
        unsigned fb = 0;
#pragma unroll
        for (int bit = 4; bit < 14; ++bit)
            if ((t >> (bit - 4)) & 1) fb ^= colm[0][bit];
#pragma unroll
        for (int k = 0; k < 16; ++k) {          // wires 10..13 from k bits
            float2 pl = rot[0][10][(((k >> 3) & 1) * 2) + ((bm >> 3) & 1)];
            pl = cmul(pl, rot[0][11][(((k >> 2) & 1) * 2) + ((bm >> 2) & 1)]);
            pl = cmul(pl, rot[0][12][(((k >> 1) & 1) * 2) + ((bm >> 1) & 1)]);
            pl = cmul(pl, rot[0][13][((k & 1) * 2) + (bm & 1)]);
            st[SLOT((int)(fb ^ flow[0][k]))] = cmul(ph, pl);
        }
    }
    __syncthreads();

    // ---- remaining 5 Rot layers, each with its trailing ring folded in.
    // Sequence after init+ring1: (l1,r2),(l0,r1),(l1,r2),(l0,r1),(l1,r2) ----
#pragma unroll 1
    for (int rep = 0; rep < 5; ++rep) {
        const int l = (rep & 1) ? 0 : 1;        // ring r = l+1 -> colm[l]/flow[l]
        rot_pass<10>(st, rot[l], t); __syncthreads();   // wires 0..3
        rot_pass<6>(st, rot[l], t);  __syncthreads();   // wires 4..7
        rot_pass<2>(st, rot[l], t);  __syncthreads();   // wires 8..11
        rot_low_ring(st, rot[l], t, colm[l], flow[l]);  // wires 12,13 + ring
        __syncthreads();
    }

    // ---- measurement: out = sum_i |psi_i|^2 * (sum_w hw[w]*(-1)^{bit_w(i)}) + hb ----
    float chi = 0.f;
#pragma unroll
    for (int w = 0; w < 10; ++w)
        chi += ((t >> (9 - w)) & 1) ? -s_hw[w] : s_hw[w];
    const float4* mp = (const float4*)(st + SLOT(t << 4));
    float acc = 0.f;
#pragma unroll
    for (int j = 0; j < 8; ++j) {
        float4 v = mp[j];
        const int ka = 2 * j, kb = 2 * j + 1;
        float cca = chi, ccb = chi;
        cca += ((ka >> 3) & 1) ? -s_hw[10] : s_hw[10];
        cca += ((ka >> 2) & 1) ? -s_hw[11] : s_hw[11];
        cca += ((ka >> 1) & 1) ? -s_hw[12] : s_hw[12];
        cca += (ka & 1)        ? -s_hw[13] : s_hw[13];
        ccb += ((kb >> 3) & 1) ? -s_hw[10] : s_hw[10];
        ccb += ((kb >> 2) & 1) ? -s_hw[11] : s_hw[11];
        ccb += ((kb >> 1) & 1) ? -s_hw[12] : s_hw[12];
        ccb += (kb & 1)        ? -s_hw[13] : s_hw[13];
        acc += (v.x * v.x + v.y * v.y) * cca;
        acc += (v.z * v.z + v.w * v.w) * ccb;
    }
    for (int off = 32; off > 0; off >>= 1) acc += __shfl_down(acc, off);
    if ((t & 63) == 0) s_red[t >> 6] = acc;
    __syncthreads();
    if (t == 0) {
        float tot = 0.f;
#pragma unroll
        for (int i = 0; i < NTHREADS / 64; ++i) tot += s_red[i];
        out[bid] = tot + hb[0];
    }
}

extern "C" void kernel_launch(void* const* d_in, const int* in_sizes, int n_in,
                              void* d_out, int out_size, void* d_ws, size_t ws_size,
                              hipStream_t stream)
{
    const float* sb = (const float*)d_in[0];   // state_batch (B, 2^14, 2) f32
    const float* pr = (const float*)d_in[1];   // params (B, 84) f32
    const float* hw = (const float*)d_in[2];   // head_w (1, 14) f32
    const float* hb = (const float*)d_in[3];   // head_b (1,) f32
    float* out = (float*)d_out;                // (B,) f32
    const int B = in_sizes[1] / 84;            // 512
    qsim<<<B, NTHREADS, 0, stream>>>(sb, pr, hw, hb, out);
}

// Round 3
// 209.516 us; speedup vs baseline: 2.2934x; 1.3636x over previous
//
#include <hip/hip_runtime.h>

// 14-qubit state-vector sim, one workgroup per batch element, state in LDS.
// Wire w <-> bit (13-w). CNOT rings folded into scatter writes.
// R3: packed fp32 (v_pk_fma_f32) SoA butterflies; XOR LDS bank swizzle
//     (no padding, b128-aligned, conflict-free contiguous pass);
//     measurement folded into last layer via compile-time ring constants.

#define NW 14
#define NSTATE (1 << NW)                      // 16384
#define NTHREADS 1024

typedef float v2f __attribute__((ext_vector_type(2)));
__device__ __forceinline__ v2f spl(float x) { return (v2f){x, x}; }
#define PKF(a, b, c) __builtin_elementwise_fma((a), (b), (c))

// Bank swizzle: XOR slot bits 1-3 with (i>>4)^(i>>7). Preserves bit0 (b64
// pairs) and 16B alignment; spreads the 128B lane stride of the contiguous
// pass across all banks.
__device__ __forceinline__ int SLOT(int i) {
    return i ^ ((((i >> 4) ^ (i >> 7)) & 7) << 1);
}

__device__ __forceinline__ float2 cmul(float2 a, float2 b) {
    return make_float2(a.x * b.x - a.y * b.y, a.x * b.y + a.y * b.x);
}

// ---- compile-time CNOT-ring constants (independent of inputs) ----
struct RingConsts { unsigned col[2][NW]; unsigned flow[2][16]; };
constexpr RingConsts make_rc() {
    RingConsts rc{};
    for (int ri = 0; ri < 2; ++ri) {
        for (int bb = 0; bb < NW; ++bb) {
            unsigned x = 1u << bb;
            for (int w = 0; w < NW; ++w) {
                int pc = 13 - w, pt = 13 - ((w + ri + 1) % NW);
                x ^= ((x >> pc) & 1u) << pt;
            }
            rc.col[ri][bb] = x;
        }
        for (int k = 0; k < 16; ++k) {
            unsigned x = 0;
            for (int b = 0; b < 4; ++b) if ((k >> b) & 1) x ^= rc.col[ri][b];
            rc.flow[ri][k] = x;
        }
    }
    return rc;
}
constexpr RingConsts RC = make_rc();

// ---- packed-math butterfly macros (SoA: RE=(re_a,re_b), IM=(im_a,im_b)) ----
#define LOADUW(w_) \
    const float4 uA = *(const float4*)&R[w_][0]; \
    const float4 uB = *(const float4*)&R[w_][2]; \
    const float u00x = uA.x, u00y = uA.y, u01x = uA.z, u01y = uA.w; \
    const float u10x = uB.x, u10y = uB.y, u11x = uB.z, u11y = uB.w;

// butterfly between pair m and pair n (2 butterflies, 16 pk ops)
#define CBF_CROSS(R0, I0, R1, I1) { \
    const v2f t0r = R0, t0i = I0, t1r = R1, t1i = I1; \
    const v2f X0 = spl(u00x), Y0 = spl(u00y), X1 = spl(u01x), Y1 = spl(u01y); \
    const v2f X2 = spl(u10x), Y2 = spl(u10y), X3 = spl(u11x), Y3 = spl(u11y); \
    R0 = PKF(t0r, X0, PKF(t0i, -Y0, PKF(t1r, X1, t1i * (-Y1)))); \
    I0 = PKF(t0r, Y0, PKF(t0i,  X0, PKF(t1r, Y1, t1i *   X1 ))); \
    R1 = PKF(t0r, X2, PKF(t0i, -Y2, PKF(t1r, X3, t1i * (-Y3)))); \
    I1 = PKF(t0r, Y2, PKF(t0i,  X2, PKF(t1r, Y3, t1i *   X3 ))); }

// butterfly within a pair (1 butterfly, 8 pk ops)
#define CBF_INTRA(Rr, Ii) { \
    const v2f rl = __builtin_shufflevector(Rr, Rr, 0, 0), rh = __builtin_shufflevector(Rr, Rr, 1, 1); \
    const v2f il = __builtin_shufflevector(Ii, Ii, 0, 0), ih = __builtin_shufflevector(Ii, Ii, 1, 1); \
    const v2f Px0 = (v2f){u00x, u10x}, Px1 = (v2f){u01x, u11x}; \
    const v2f Py0 = (v2f){u00y, u10y}, Py1 = (v2f){u01y, u11y}; \
    Rr = PKF(rl, Px0, PKF(rh, Px1, PKF(il, -Py0, ih * (-Py1)))); \
    Ii = PKF(rl, Py0, PKF(rh, Py1, PKF(il,  Px0, ih *   Px1 ))); }

// Apply 4 Rot gates (k-bits 3..0 = wires 10-LO..13-LO) to 16 amps/thread.
template<int LO>
__device__ __forceinline__ void rot_pass(float2* st_, const float2 (*R)[4], int t)
{
    const int lowmask = (1 << LO) - 1;
    const int base = ((t >> LO) << (LO + 4)) | (t & lowmask);
#define LD2(j) \
    const float2 eA##j = st_[SLOT(base | ((2*j) << LO))]; \
    const float2 eB##j = st_[SLOT(base | ((2*j+1) << LO))]; \
    v2f RE##j = (v2f){eA##j.x, eB##j.x}, IM##j = (v2f){eA##j.y, eB##j.y};
    LD2(0) LD2(1) LD2(2) LD2(3) LD2(4) LD2(5) LD2(6) LD2(7)
#undef LD2
    {   LOADUW(10 - LO)   // k-bit 3: pairs (j, j+4)
        CBF_CROSS(RE0, IM0, RE4, IM4) CBF_CROSS(RE1, IM1, RE5, IM5)
        CBF_CROSS(RE2, IM2, RE6, IM6) CBF_CROSS(RE3, IM3, RE7, IM7) }
    {   LOADUW(11 - LO)   // k-bit 2: pairs (j, j+2)
        CBF_CROSS(RE0, IM0, RE2, IM2) CBF_CROSS(RE1, IM1, RE3, IM3)
        CBF_CROSS(RE4, IM4, RE6, IM6) CBF_CROSS(RE5, IM5, RE7, IM7) }
    {   LOADUW(12 - LO)   // k-bit 1: pairs (j, j+1)
        CBF_CROSS(RE0, IM0, RE1, IM1) CBF_CROSS(RE2, IM2, RE3, IM3)
        CBF_CROSS(RE4, IM4, RE5, IM5) CBF_CROSS(RE6, IM6, RE7, IM7) }
    {   LOADUW(13 - LO)   // k-bit 0: intra-pair
        CBF_INTRA(RE0, IM0) CBF_INTRA(RE1, IM1) CBF_INTRA(RE2, IM2) CBF_INTRA(RE3, IM3)
        CBF_INTRA(RE4, IM4) CBF_INTRA(RE5, IM5) CBF_INTRA(RE6, IM6) CBF_INTRA(RE7, IM7) }
#define ST2(j) \
    st_[SLOT(base | ((2*j) << LO))]   = make_float2(RE##j.x, IM##j.x); \
    st_[SLOT(base | ((2*j+1) << LO))] = make_float2(RE##j.y, IM##j.y);
    ST2(0) ST2(1) ST2(2) ST2(3) ST2(4) ST2(5) ST2(6) ST2(7)
#undef ST2
}

// common low-pass load + wires 12,13 (contiguous b128, swizzle-aware)
#define LOW_LOAD_AND_GATES \
    const int c = (t & 7) ^ ((t >> 3) & 7); \
    const float4* lp = (const float4*)(st_ + (t << 4)); \
    float4 v0 = lp[0 ^ c], v1 = lp[1 ^ c], v2 = lp[2 ^ c], v3 = lp[3 ^ c], \
           v4 = lp[4 ^ c], v5 = lp[5 ^ c], v6 = lp[6 ^ c], v7 = lp[7 ^ c]; \
    v2f RE0 = (v2f){v0.x, v0.z}, IM0 = (v2f){v0.y, v0.w}; \
    v2f RE1 = (v2f){v1.x, v1.z}, IM1 = (v2f){v1.y, v1.w}; \
    v2f RE2 = (v2f){v2.x, v2.z}, IM2 = (v2f){v2.y, v2.w}; \
    v2f RE3 = (v2f){v3.x, v3.z}, IM3 = (v2f){v3.y, v3.w}; \
    v2f RE4 = (v2f){v4.x, v4.z}, IM4 = (v2f){v4.y, v4.w}; \
    v2f RE5 = (v2f){v5.x, v5.z}, IM5 = (v2f){v5.y, v5.w}; \
    v2f RE6 = (v2f){v6.x, v6.z}, IM6 = (v2f){v6.y, v6.w}; \
    v2f RE7 = (v2f){v7.x, v7.z}, IM7 = (v2f){v7.y, v7.w}; \
    {   LOADUW(12)  /* k-bit 1 */ \
        CBF_CROSS(RE0, IM0, RE1, IM1) CBF_CROSS(RE2, IM2, RE3, IM3) \
        CBF_CROSS(RE4, IM4, RE5, IM5) CBF_CROSS(RE6, IM6, RE7, IM7) } \
    {   LOADUW(13)  /* k-bit 0 */ \
        CBF_INTRA(RE0, IM0) CBF_INTRA(RE1, IM1) CBF_INTRA(RE2, IM2) CBF_INTRA(RE3, IM3) \
        CBF_INTRA(RE4, IM4) CBF_INTRA(RE5, IM5) CBF_INTRA(RE6, IM6) CBF_INTRA(RE7, IM7) }

// wires 12,13 + ring permutation folded into scatter (reps 0..3)
__device__ __forceinline__ void rot_low_ring(float2* st_, const float2 (*R)[4], int t,
                                             const unsigned* colr, const unsigned* flowr)
{
    LOW_LOAD_AND_GATES
    unsigned fb = 0;
#pragma unroll
    for (int bit = 4; bit < 14; ++bit)
        if ((t >> (bit - 4)) & 1) fb ^= colr[bit];
    __syncthreads();                            // all reads done before scatter
#define SC2(j) \
    st_[SLOT((int)(fb ^ flowr[2*j]))]   = make_float2(RE##j.x, IM##j.x); \
    st_[SLOT((int)(fb ^ flowr[2*j+1]))] = make_float2(RE##j.y, IM##j.y);
    SC2(0) SC2(1) SC2(2) SC2(3) SC2(4) SC2(5) SC2(6) SC2(7)
#undef SC2
}

// final layer: wires 12,13 + ring + <Z> measurement, no writeback (l=1 ring)
__device__ __forceinline__ float rot_low_meas(float2* st_, const float2 (*R)[4], int t,
                                              const float* s_hw)
{
    LOW_LOAD_AND_GATES
    unsigned fb = 0;
#pragma unroll
    for (int bit = 4; bit < 14; ++bit)
        if ((t >> (bit - 4)) & 1) fb ^= RC.col[1][bit];
    // sigma_b = hw[13-b] * (-1)^{fb_b}; chi(idx) for idx = fb ^ flow[1][k]
#define SGV(b) ((((fb >> b) & 1u) ? -1.f : 1.f) * s_hw[13 - (b)])
    const float sg0 = SGV(0),  sg1 = SGV(1),  sg2 = SGV(2),  sg3 = SGV(3),
                sg4 = SGV(4),  sg5 = SGV(5),  sg6 = SGV(6),  sg7 = SGV(7),
                sg8 = SGV(8),  sg9 = SGV(9),  sg10 = SGV(10), sg11 = SGV(11),
                sg12 = SGV(12), sg13 = SGV(13);
#undef SGV
    const float chiS = ((sg0 + sg1) + (sg2 + sg3)) + ((sg4 + sg5) + (sg6 + sg7))
                     + ((sg8 + sg9) + (sg10 + sg11)) + (sg12 + sg13);
#define SUBSUM(F) ( ((F)&1u?sg0:0.f) + ((F)&2u?sg1:0.f) + ((F)&4u?sg2:0.f) + ((F)&8u?sg3:0.f) \
                  + ((F)&16u?sg4:0.f) + ((F)&32u?sg5:0.f) + ((F)&64u?sg6:0.f) + ((F)&128u?sg7:0.f) \
                  + ((F)&256u?sg8:0.f) + ((F)&512u?sg9:0.f) + ((F)&1024u?sg10:0.f) + ((F)&2048u?sg11:0.f) \
                  + ((F)&4096u?sg12:0.f) + ((F)&8192u?sg13:0.f) )
    v2f acc2 = (v2f){0.f, 0.f};
#define MEAS(j) { \
    const v2f p = PKF(RE##j, RE##j, IM##j * IM##j); \
    const v2f wv = (v2f){ chiS - 2.f * SUBSUM(RC.flow[1][2*j]), \
                          chiS - 2.f * SUBSUM(RC.flow[1][2*j+1]) }; \
    acc2 = PKF(p, wv, acc2); }
    MEAS(0) MEAS(1) MEAS(2) MEAS(3) MEAS(4) MEAS(5) MEAS(6) MEAS(7)
#undef MEAS
#undef SUBSUM
    return acc2.x + acc2.y;
}

__global__ __launch_bounds__(NTHREADS)
__attribute__((amdgpu_waves_per_eu(4, 4)))
void qsim(const float* __restrict__ sb, const float* __restrict__ pr,
          const float* __restrict__ hw, const float* __restrict__ hb,
          float* __restrict__ out)
{
    __shared__ __align__(16) float2 st[NSTATE];        // 131072 B, no pad (XOR swizzle)
    __shared__ __align__(16) float2 rot[2][NW][4];     // Rot matrices per (layer, wire)
    __shared__ unsigned colm[2][NW];                   // ring columns (for rolled loop)
    __shared__ unsigned flow[2][16];
    __shared__ float s_hw[NW];
    __shared__ float s_red[NTHREADS / 64];
    __shared__ unsigned s_bmask;

    const int bid = blockIdx.x;
    const int t = threadIdx.x;

    // ---- setup ----
    if (t < 28) {
        int l = t / NW, w = t % NW;
        const float* p = pr + bid * 84 + l * 42 + w * 3;
        float phi = p[0], th = p[1], om = p[2];
        float s, cth;  __sincosf(0.5f * th, &s, &cth);
        float sa, ca, sd, cd;
        __sincosf(0.5f * (phi + om), &sa, &ca);
        __sincosf(0.5f * (phi - om), &sd, &cd);
        rot[l][w][0] = make_float2(ca * cth, -sa * cth);
        rot[l][w][1] = make_float2(-cd * s, -sd * s);
        rot[l][w][2] = make_float2(cd * s, -sd * s);
        rot[l][w][3] = make_float2(ca * cth, sa * cth);
    }
    if (t >= 64 && t < 92) {                    // LDS copies of ring constants
        int j = t - 64, ri = j / NW, bb = j % NW;
        colm[ri][bb] = RC.col[ri][bb];
    }
    if (t >= 96 && t < 128) {
        int j = t - 96;
        flow[j >> 4][j & 15] = RC.flow[j >> 4][j & 15];
    }
    if (t >= 128 && t < 142) s_hw[t - 128] = hw[t - 128];
    if (t == 192) {                             // basis index from sign bits
        const float* row = sb + (size_t)bid * (NSTATE * 2);
        unsigned m = 0;
        for (int w = 0; w < NW; ++w) m |= (row[w] < 0.0f ? 1u : 0u) << (13 - w);
        s_bmask = m;
    }
    __syncthreads();

    // ---- init: layer 0 on basis state |bm> (product state), ring r=1 folded ----
    {
        const unsigned bm = s_bmask;
        float2 ph = make_float2(1.f, 0.f);
#pragma unroll
        for (int w = 0; w < 10; ++w) {
            int v = (t >> (9 - w)) & 1;
            int bw = (bm >> (13 - w)) & 1;
            ph = cmul(ph, rot[0][w][v * 2 + bw]);
        }
        unsigned fb = 0;
#pragma unroll
        for (int bit = 4; bit < 14; ++bit)
            if ((t >> (bit - 4)) & 1) fb ^= RC.col[0][bit];
#pragma unroll
        for (int k = 0; k < 16; ++k) {
            float2 pl = rot[0][10][(((k >> 3) & 1) * 2) + ((bm >> 3) & 1)];
            pl = cmul(pl, rot[0][11][(((k >> 2) & 1) * 2) + ((bm >> 2) & 1)]);
            pl = cmul(pl, rot[0][12][(((k >> 1) & 1) * 2) + ((bm >> 1) & 1)]);
            pl = cmul(pl, rot[0][13][((k & 1) * 2) + (bm & 1)]);
            st[SLOT((int)(fb ^ RC.flow[0][k]))] = cmul(ph, pl);
        }
    }
    __syncthreads();

    // ---- reps 0..3: layers (1,0,1,0) each with trailing ring folded in ----
#pragma unroll 1
    for (int rep = 0; rep < 4; ++rep) {
        const int l = (rep & 1) ? 0 : 1;
        rot_pass<10>(st, rot[l], t); __syncthreads();
        rot_pass<6>(st, rot[l], t);  __syncthreads();
        rot_pass<2>(st, rot[l], t);  __syncthreads();
        rot_low_ring(st, rot[l], t, colm[l], flow[l]);
        __syncthreads();
    }
    // ---- rep 4: layer 1, ring r=2 + measurement folded (no writeback) ----
    rot_pass<10>(st, rot[1], t); __syncthreads();
    rot_pass<6>(st, rot[1], t);  __syncthreads();
    rot_pass<2>(st, rot[1], t);  __syncthreads();
    float acc = rot_low_meas(st, rot[1], t, s_hw);

    for (int off = 32; off > 0; off >>= 1) acc += __shfl_down(acc, off);
    if ((t & 63) == 0) s_red[t >> 6] = acc;
    __syncthreads();
    if (t == 0) {
        float tot = 0.f;
#pragma unroll
        for (int i = 0; i < NTHREADS / 64; ++i) tot += s_red[i];
        out[bid] = tot + hb[0];
    }
}

extern "C" void kernel_launch(void* const* d_in, const int* in_sizes, int n_in,
                              void* d_out, int out_size, void* d_ws, size_t ws_size,
                              hipStream_t stream)
{
    const float* sb = (const float*)d_in[0];   // state_batch (B, 2^14, 2) f32
    const float* pr = (const float*)d_in[1];   // params (B, 84) f32
    const float* hw = (const float*)d_in[2];   // head_w (1, 14) f32
    const float* hb = (const float*)d_in[3];   // head_b (1,) f32
    float* out = (float*)d_out;                // (B,) f32
    const int B = in_sizes[1] / 84;            // 512
    qsim<<<B, NTHREADS, 0, stream>>>(sb, pr, hw, hb, out);
}

// Round 5
// 208.911 us; speedup vs baseline: 2.3001x; 1.0029x over previous
//
#include <hip/hip_runtime.h>

// 14-qubit state-vector sim, one workgroup per batch element, state in LDS.
// Wire w <-> bit (13-w). CNOT rings folded into scatter writes.
// R5: R4 with the gate-constant fix: per gate u we store {u.re, u.im, -u.im,
//     +u.im} (R4 wrongly stored .w = u.re -> non-unitary butterfly, blowup).
//     AoS complex packed math via v_pk_fma_f32 + op_sel; padded LDS layout
//     (+2 float2 / 64 amps) -> affine-in-k ds offsets, conflict-free gathers;
//     ring fb via 32-entry LUTs; flow as compile-time immediates.

#define NW 14
#define NSTATE (1 << NW)                      // 16384
#define NTHREADS 1024
#define STATE_SLOTS (NSTATE + ((NSTATE >> 6) << 1))   // 16896 float2

__device__ __forceinline__ int SLOT(int i) { return i + ((i >> 6) << 1); }

typedef float v2f __attribute__((ext_vector_type(2)));

__device__ __forceinline__ float2 cmul(float2 a, float2 b) {
    return make_float2(a.x * b.x - a.y * b.y, a.x * b.y + a.y * b.x);
}

// ---- VOP3P packed f32 helpers (op_sel bit i: which half of src i feeds the
//      LOW result lane; op_sel_hi: the HIGH result lane) ----
__device__ __forceinline__ v2f pk_mul_bl(v2f a, v2f b) {   // {a.lo*b.lo, a.hi*b.lo}
    v2f d;
    asm("v_pk_mul_f32 %0, %1, %2 op_sel:[0,0] op_sel_hi:[1,0]"
        : "=v"(d) : "v"(a), "v"(b));
    return d;
}
__device__ __forceinline__ v2f pk_fma_bl(v2f a, v2f b, v2f c) { // {a.lo*b.lo+c.lo, a.hi*b.lo+c.hi}
    v2f d;
    asm("v_pk_fma_f32 %0, %1, %2, %3 op_sel:[0,0,0] op_sel_hi:[1,0,1]"
        : "=v"(d) : "v"(a), "v"(b), "v"(c));
    return d;
}
__device__ __forceinline__ v2f pk_fma_sw(v2f a, v2f b, v2f c) { // {a.hi*b.lo+c.lo, a.lo*b.hi+c.hi}
    v2f d;
    asm("v_pk_fma_f32 %0, %1, %2, %3 op_sel:[1,0,0] op_sel_hi:[0,1,1]"
        : "=v"(d) : "v"(a), "v"(b), "v"(c));
    return d;
}

// ---- compile-time CNOT-ring constants ----
struct RingConsts { unsigned col[2][NW]; unsigned flow[2][16]; };
constexpr RingConsts make_rc() {
    RingConsts rc{};
    for (int ri = 0; ri < 2; ++ri) {
        for (int bb = 0; bb < NW; ++bb) {
            unsigned x = 1u << bb;
            for (int w = 0; w < NW; ++w) {
                int pc = 13 - w, pt = 13 - ((w + ri + 1) % NW);
                x ^= ((x >> pc) & 1u) << pt;
            }
            rc.col[ri][bb] = x;
        }
        for (int k = 0; k < 16; ++k) {
            unsigned x = 0;
            for (int b = 0; b < 4; ++b) if ((k >> b) & 1) x ^= rc.col[ri][b];
            rc.flow[ri][k] = x;
        }
    }
    return rc;
}
constexpr RingConsts RC = make_rc();

// Gate constants for wire W from G4 (4 float4 per gate:
//  {u.re, u.im, -u.im, +u.im} for u00,u01,u10,u11)
#define GSTAGE(W) \
    const float4 g0 = G4[(W)*4+0], g1 = G4[(W)*4+1], \
                 g2 = G4[(W)*4+2], g3 = G4[(W)*4+3]; \
    const v2f U00 = (v2f){g0.x,g0.y}, V00 = (v2f){g0.z,g0.w}; \
    const v2f U01 = (v2f){g1.x,g1.y}, V01 = (v2f){g1.z,g1.w}; \
    const v2f U10 = (v2f){g2.x,g2.y}, V10 = (v2f){g2.z,g2.w}; \
    const v2f U11 = (v2f){g3.x,g3.y}, V11 = (v2f){g3.z,g3.w};

// complex butterfly on amps X={r,i}, Y: X' = u00*X+u01*Y; Y' = u10*X+u11*Y
//  re' = u.re*x.re - u.im*x.im + ... ;  im' = u.im*x.re + u.re*x.im + ...
#define CBFA(X, Y) { \
    v2f n0 = pk_mul_bl(X, U00); n0 = pk_fma_sw(X, V00, n0); \
    n0 = pk_fma_bl(Y, U01, n0); n0 = pk_fma_sw(Y, V01, n0); \
    v2f n1 = pk_mul_bl(X, U10); n1 = pk_fma_sw(X, V10, n1); \
    n1 = pk_fma_bl(Y, U11, n1); n1 = pk_fma_sw(Y, V11, n1); \
    X = n0; Y = n1; }

// Apply 4 Rot gates (k-bits 3..0 = wires 13-LO-3..13-LO), 16 amps/thread.
// Padded layout -> slot stride S affine in k -> single base + imm offsets.
template<int LO>
__device__ __forceinline__ void rot_pass(float2* st_, const float4* G4, int t)
{
    constexpr int S = (1 << LO) + ((LO >= 6) ? (1 << (LO - 5)) : 0);
    const int lowmask = (1 << LO) - 1;
    const int base = ((t >> LO) << (LO + 4)) | (t & lowmask);
    float2* p = st_ + SLOT(base);
    float2* q = p + 8 * S;
    v2f A0  = *(const v2f*)(p + 0*S), A1  = *(const v2f*)(p + 1*S),
        A2  = *(const v2f*)(p + 2*S), A3  = *(const v2f*)(p + 3*S),
        A4  = *(const v2f*)(p + 4*S), A5  = *(const v2f*)(p + 5*S),
        A6  = *(const v2f*)(p + 6*S), A7  = *(const v2f*)(p + 7*S),
        A8  = *(const v2f*)(q + 0*S), A9  = *(const v2f*)(q + 1*S),
        A10 = *(const v2f*)(q + 2*S), A11 = *(const v2f*)(q + 3*S),
        A12 = *(const v2f*)(q + 4*S), A13 = *(const v2f*)(q + 5*S),
        A14 = *(const v2f*)(q + 6*S), A15 = *(const v2f*)(q + 7*S);
    { GSTAGE(13 - LO - 3)   // k-bit 3
      CBFA(A0,A8) CBFA(A1,A9) CBFA(A2,A10) CBFA(A3,A11)
      CBFA(A4,A12) CBFA(A5,A13) CBFA(A6,A14) CBFA(A7,A15) }
    { GSTAGE(13 - LO - 2)   // k-bit 2
      CBFA(A0,A4) CBFA(A1,A5) CBFA(A2,A6) CBFA(A3,A7)
      CBFA(A8,A12) CBFA(A9,A13) CBFA(A10,A14) CBFA(A11,A15) }
    { GSTAGE(13 - LO - 1)   // k-bit 1
      CBFA(A0,A2) CBFA(A1,A3) CBFA(A4,A6) CBFA(A5,A7)
      CBFA(A8,A10) CBFA(A9,A11) CBFA(A12,A14) CBFA(A13,A15) }
    { GSTAGE(13 - LO)       // k-bit 0
      CBFA(A0,A1) CBFA(A2,A3) CBFA(A4,A5) CBFA(A6,A7)
      CBFA(A8,A9) CBFA(A10,A11) CBFA(A12,A13) CBFA(A14,A15) }
    *(v2f*)(p + 0*S) = A0;  *(v2f*)(p + 1*S) = A1;
    *(v2f*)(p + 2*S) = A2;  *(v2f*)(p + 3*S) = A3;
    *(v2f*)(p + 4*S) = A4;  *(v2f*)(p + 5*S) = A5;
    *(v2f*)(p + 6*S) = A6;  *(v2f*)(p + 7*S) = A7;
    *(v2f*)(q + 0*S) = A8;  *(v2f*)(q + 1*S) = A9;
    *(v2f*)(q + 2*S) = A10; *(v2f*)(q + 3*S) = A11;
    *(v2f*)(q + 4*S) = A12; *(v2f*)(q + 5*S) = A13;
    *(v2f*)(q + 6*S) = A14; *(v2f*)(q + 7*S) = A15;
}

// contiguous load of 16 amps + gates on wires 12 (bit1), 13 (bit0)
#define LOW_LOAD_GATES \
    float2* pc = st_ + SLOT(t << 4); \
    const float4* lp = (const float4*)pc; \
    const float4 r0 = lp[0], r1 = lp[1], r2 = lp[2], r3 = lp[3], \
                 r4 = lp[4], r5 = lp[5], r6 = lp[6], r7 = lp[7]; \
    v2f A0  = (v2f){r0.x,r0.y}, A1  = (v2f){r0.z,r0.w}, \
        A2  = (v2f){r1.x,r1.y}, A3  = (v2f){r1.z,r1.w}, \
        A4  = (v2f){r2.x,r2.y}, A5  = (v2f){r2.z,r2.w}, \
        A6  = (v2f){r3.x,r3.y}, A7  = (v2f){r3.z,r3.w}, \
        A8  = (v2f){r4.x,r4.y}, A9  = (v2f){r4.z,r4.w}, \
        A10 = (v2f){r5.x,r5.y}, A11 = (v2f){r5.z,r5.w}, \
        A12 = (v2f){r6.x,r6.y}, A13 = (v2f){r6.z,r6.w}, \
        A14 = (v2f){r7.x,r7.y}, A15 = (v2f){r7.z,r7.w}; \
    { GSTAGE(12) \
      CBFA(A0,A2) CBFA(A1,A3) CBFA(A4,A6) CBFA(A5,A7) \
      CBFA(A8,A10) CBFA(A9,A11) CBFA(A12,A14) CBFA(A13,A15) } \
    { GSTAGE(13) \
      CBFA(A0,A1) CBFA(A2,A3) CBFA(A4,A5) CBFA(A6,A7) \
      CBFA(A8,A9) CBFA(A10,A11) CBFA(A12,A13) CBFA(A14,A15) }

// wires 12,13 + ring permutation folded into scatter
template<int RI>
__device__ __forceinline__ void rot_low_ring(float2* st_, const float4* G4, int t,
                                             const unsigned* lutA_, const unsigned* lutB_)
{
    LOW_LOAD_GATES
    const unsigned fb = lutA_[t & 31] ^ lutB_[t >> 5];
    __syncthreads();                            // all reads done before scatter
#define SCT(k, Ak) st_[SLOT((int)(fb ^ RC.flow[RI][k]))] = make_float2(Ak.x, Ak.y);
    SCT(0,A0) SCT(1,A1) SCT(2,A2) SCT(3,A3) SCT(4,A4) SCT(5,A5) SCT(6,A6) SCT(7,A7)
    SCT(8,A8) SCT(9,A9) SCT(10,A10) SCT(11,A11) SCT(12,A12) SCT(13,A13) SCT(14,A14) SCT(15,A15)
#undef SCT
}

// final layer: wires 12,13 + ring(RI=1) + <Z> measurement, no writeback
__device__ __forceinline__ float rot_low_meas(float2* st_, const float4* G4, int t,
                                              const unsigned* lutA_, const unsigned* lutB_,
                                              const float* s_hw)
{
    LOW_LOAD_GATES
    const unsigned fb = lutA_[t & 31] ^ lutB_[t >> 5];
#define SGV(b) ((((fb >> b) & 1u) ? -1.f : 1.f) * s_hw[13 - (b)])
    const float sg0 = SGV(0),  sg1 = SGV(1),  sg2 = SGV(2),  sg3 = SGV(3),
                sg4 = SGV(4),  sg5 = SGV(5),  sg6 = SGV(6),  sg7 = SGV(7),
                sg8 = SGV(8),  sg9 = SGV(9),  sg10 = SGV(10), sg11 = SGV(11),
                sg12 = SGV(12), sg13 = SGV(13);
#undef SGV
    const float chiS = ((sg0 + sg1) + (sg2 + sg3)) + ((sg4 + sg5) + (sg6 + sg7))
                     + ((sg8 + sg9) + (sg10 + sg11)) + (sg12 + sg13);
#define SUBSUM(F) ( ((F)&1u?sg0:0.f) + ((F)&2u?sg1:0.f) + ((F)&4u?sg2:0.f) + ((F)&8u?sg3:0.f) \
                  + ((F)&16u?sg4:0.f) + ((F)&32u?sg5:0.f) + ((F)&64u?sg6:0.f) + ((F)&128u?sg7:0.f) \
                  + ((F)&256u?sg8:0.f) + ((F)&512u?sg9:0.f) + ((F)&1024u?sg10:0.f) + ((F)&2048u?sg11:0.f) \
                  + ((F)&4096u?sg12:0.f) + ((F)&8192u?sg13:0.f) )
    float acc = 0.f;
#define MEASA(k, Ak) { const float p2 = fmaf(Ak.x, Ak.x, Ak.y * Ak.y); \
    acc = fmaf(p2, chiS - 2.f * SUBSUM(RC.flow[1][k]), acc); }
    MEASA(0,A0) MEASA(1,A1) MEASA(2,A2) MEASA(3,A3)
    MEASA(4,A4) MEASA(5,A5) MEASA(6,A6) MEASA(7,A7)
    MEASA(8,A8) MEASA(9,A9) MEASA(10,A10) MEASA(11,A11)
    MEASA(12,A12) MEASA(13,A13) MEASA(14,A14) MEASA(15,A15)
#undef MEASA
#undef SUBSUM
    return acc;
}

__global__ __launch_bounds__(NTHREADS)
__attribute__((amdgpu_waves_per_eu(4, 4)))
void qsim(const float* __restrict__ sb, const float* __restrict__ pr,
          const float* __restrict__ hw, const float* __restrict__ hb,
          float* __restrict__ out)
{
    __shared__ __align__(16) float2 st[STATE_SLOTS];     // 135,168 B
    __shared__ __align__(16) float4 rotc[2][NW * 4];     // 1792 B gate consts
    __shared__ unsigned lutA[2][32], lutB[2][32];        // ring fb LUTs
    __shared__ float s_hw[NW];
    __shared__ float s_red[NTHREADS / 64];
    __shared__ unsigned s_bmask;

    const int bid = blockIdx.x;
    const int t = threadIdx.x;

    // ---- setup ----
    if (t < 28) {
        int l = t / NW, w = t % NW;
        const float* p = pr + bid * 84 + l * 42 + w * 3;
        float phi = p[0], th = p[1], om = p[2];
        float s, cth;  __sincosf(0.5f * th, &s, &cth);
        float sa, ca, sd, cd;
        __sincosf(0.5f * (phi + om), &sa, &ca);
        __sincosf(0.5f * (phi - om), &sd, &cd);
        const float u00x = ca * cth, u00y = -sa * cth;
        const float u01x = -cd * s,  u01y = -sd * s;
        const float u10x = cd * s,   u10y = -sd * s;
        const float u11x = ca * cth, u11y = sa * cth;
        rotc[l][w*4+0] = make_float4(u00x, u00y, -u00y, u00y);   // {re, im, -im, +im}
        rotc[l][w*4+1] = make_float4(u01x, u01y, -u01y, u01y);
        rotc[l][w*4+2] = make_float4(u10x, u10y, -u10y, u10y);
        rotc[l][w*4+3] = make_float4(u11x, u11y, -u11y, u11y);
    }
    if (t >= 64 && t < 192) {                   // fb LUTs: i-bits 4-8 / 9-13
        int j = t - 64, ri = j >> 6, tb = (j >> 5) & 1, m = j & 31;
        unsigned x = 0;
        for (int b = 0; b < 5; ++b)
            if ((m >> b) & 1) x ^= RC.col[ri][(tb ? 9 : 4) + b];
        if (tb) lutB[ri][m] = x; else lutA[ri][m] = x;
    }
    if (t >= 192 && t < 206) s_hw[t - 192] = hw[t - 192];
    if (t == 224) {                             // basis index from sign bits
        const float* row = sb + (size_t)bid * (NSTATE * 2);
        unsigned m = 0;
        for (int w = 0; w < NW; ++w) m |= (row[w] < 0.0f ? 1u : 0u) << (13 - w);
        s_bmask = m;
    }
    __syncthreads();

    // ---- init: layer 0 on basis state |bm> (product state), ring r=1 folded ----
    {
        const unsigned bm = s_bmask;
        float2 ph = make_float2(1.f, 0.f);
#pragma unroll
        for (int w = 0; w < 10; ++w) {
            int v = (t >> (9 - w)) & 1;
            int bw = (bm >> (13 - w)) & 1;
            float4 e = rotc[0][w*4 + v*2 + bw];
            ph = cmul(ph, make_float2(e.x, e.y));
        }
        const unsigned fb = lutA[0][t & 31] ^ lutB[0][t >> 5];
#pragma unroll
        for (int k = 0; k < 16; ++k) {
            float4 e3 = rotc[0][10*4 + (((k >> 3) & 1) * 2) + ((bm >> 3) & 1)];
            float4 e2 = rotc[0][11*4 + (((k >> 2) & 1) * 2) + ((bm >> 2) & 1)];
            float4 e1 = rotc[0][12*4 + (((k >> 1) & 1) * 2) + ((bm >> 1) & 1)];
            float4 e0 = rotc[0][13*4 + ((k & 1) * 2) + (bm & 1)];
            float2 pl = cmul(cmul(make_float2(e3.x, e3.y), make_float2(e2.x, e2.y)),
                             cmul(make_float2(e1.x, e1.y), make_float2(e0.x, e0.y)));
            st[SLOT((int)(fb ^ RC.flow[0][k]))] = cmul(ph, pl);
        }
    }
    __syncthreads();

    // ---- reps 0..3: layers (1,0,1,0), trailing ring folded in ----
#pragma unroll 1
    for (int rep = 0; rep < 4; ++rep) {
        const int l = (rep & 1) ? 0 : 1;
        const float4* G4 = &rotc[l][0];
        rot_pass<10>(st, G4, t); __syncthreads();
        rot_pass<6>(st, G4, t);  __syncthreads();
        rot_pass<2>(st, G4, t);  __syncthreads();
        if (l) rot_low_ring<1>(st, G4, t, lutA[1], lutB[1]);
        else   rot_low_ring<0>(st, G4, t, lutA[0], lutB[0]);
        __syncthreads();
    }
    // ---- rep 4: layer 1, ring r=2 + measurement folded (no writeback) ----
    rot_pass<10>(st, &rotc[1][0], t); __syncthreads();
    rot_pass<6>(st, &rotc[1][0], t); __syncthreads();
    rot_pass<2>(st, &rotc[1][0], t); __syncthreads();
    float acc = rot_low_meas(st, &rotc[1][0], t, lutA[1], lutB[1], s_hw);

    for (int off = 32; off > 0; off >>= 1) acc += __shfl_down(acc, off);
    if ((t & 63) == 0) s_red[t >> 6] = acc;
    __syncthreads();
    if (t == 0) {
        float tot = 0.f;
#pragma unroll
        for (int i = 0; i < NTHREADS / 64; ++i) tot += s_red[i];
        out[bid] = tot + hb[0];
    }
}

extern "C" void kernel_launch(void* const* d_in, const int* in_sizes, int n_in,
                              void* d_out, int out_size, void* d_ws, size_t ws_size,
                              hipStream_t stream)
{
    const float* sb = (const float*)d_in[0];   // state_batch (B, 2^14, 2) f32
    const float* pr = (const float*)d_in[1];   // params (B, 84) f32
    const float* hw = (const float*)d_in[2];   // head_w (1, 14) f32
    const float* hb = (const float*)d_in[3];   // head_b (1,) f32
    float* out = (float*)d_out;                // (B,) f32
    const int B = in_sizes[1] / 84;            // 512
    qsim<<<B, NTHREADS, 0, stream>>>(sb, pr, hw, hb, out);
}

// Round 7
// 196.566 us; speedup vs baseline: 2.4445x; 1.0628x over previous
//
#include <hip/hip_runtime.h>

// 14-qubit state-vector sim, one workgroup per batch element, state in LDS.
// Wire w <-> bit (13-w). CNOT rings folded into scatter writes.
// R7: R6 (512 thr x 32 amps, 3 passes/layer) with two fixes vs R6's false
//     bit-range claim: ring/init scatter uses full XOR + SLOT (ring columns
//     are NOT confined to low/high bit ranges), and measurement weights use
//     the full 14-bit flow correction (R5-verified scheme).

#define NW 14
#define NSTATE (1 << NW)                      // 16384
#define NTHREADS 512
#define STATE_SLOTS (NSTATE + ((NSTATE >> 6) << 1))   // 16896 float2

typedef float v2f __attribute__((ext_vector_type(2)));

__device__ __forceinline__ float2 cmul(float2 a, float2 b) {
    return make_float2(a.x * b.x - a.y * b.y, a.x * b.y + a.y * b.x);
}

// ---- VOP3P packed helpers (verified R5 semantics) ----
__device__ __forceinline__ v2f pk_mul_bl(v2f a, v2f b) {   // {a.lo*b.lo, a.hi*b.lo}
    v2f d; asm("v_pk_mul_f32 %0, %1, %2 op_sel:[0,0] op_sel_hi:[1,0]"
               : "=v"(d) : "v"(a), "v"(b)); return d;
}
__device__ __forceinline__ v2f pk_fma_bl(v2f a, v2f b, v2f c) {
    v2f d; asm("v_pk_fma_f32 %0, %1, %2, %3 op_sel:[0,0,0] op_sel_hi:[1,0,1]"
               : "=v"(d) : "v"(a), "v"(b), "v"(c)); return d;
}
__device__ __forceinline__ v2f pk_fma_sw(v2f a, v2f b, v2f c) { // {a.hi*b.lo+c.lo, a.lo*b.hi+c.hi}
    v2f d; asm("v_pk_fma_f32 %0, %1, %2, %3 op_sel:[1,0,0] op_sel_hi:[0,1,1]"
               : "=v"(d) : "v"(a), "v"(b), "v"(c)); return d;
}

// ---- compile-time CNOT-ring constants ----
struct RingConsts { unsigned col[2][NW]; unsigned flow[2][32]; };
constexpr RingConsts make_rc() {
    RingConsts rc{};
    for (int ri = 0; ri < 2; ++ri) {
        for (int bb = 0; bb < NW; ++bb) {
            unsigned x = 1u << bb;
            for (int w = 0; w < NW; ++w) {
                int pc = 13 - w, pt = 13 - ((w + ri + 1) % NW);
                x ^= ((x >> pc) & 1u) << pt;
            }
            rc.col[ri][bb] = x;
        }
        for (int k = 0; k < 32; ++k) {
            unsigned x = 0;
            for (int b = 0; b < 5; ++b) if ((k >> b) & 1) x ^= rc.col[ri][b];
            rc.flow[ri][k] = x;
        }
    }
    return rc;
}
constexpr RingConsts RC = make_rc();

// Gate consts per wire W (4 float4 per gate: {u.re, u.im, -u.im, +u.im})
#define GSTAGE(W) \
    const float4 g0 = G4[(W)*4+0], g1 = G4[(W)*4+1], \
                 g2 = G4[(W)*4+2], g3 = G4[(W)*4+3]; \
    const v2f U00 = (v2f){g0.x,g0.y}, V00 = (v2f){g0.z,g0.w}; \
    const v2f U01 = (v2f){g1.x,g1.y}, V01 = (v2f){g1.z,g1.w}; \
    const v2f U10 = (v2f){g2.x,g2.y}, V10 = (v2f){g2.z,g2.w}; \
    const v2f U11 = (v2f){g3.x,g3.y}, V11 = (v2f){g3.z,g3.w};

#define CBFA(X, Y) { \
    v2f n0 = pk_mul_bl(X, U00); n0 = pk_fma_sw(X, V00, n0); \
    n0 = pk_fma_bl(Y, U01, n0); n0 = pk_fma_sw(Y, V01, n0); \
    v2f n1 = pk_mul_bl(X, U10); n1 = pk_fma_sw(X, V10, n1); \
    n1 = pk_fma_bl(Y, U11, n1); n1 = pk_fma_sw(Y, V11, n1); \
    X = n0; Y = n1; }

#define FE32(M) M(0) M(1) M(2) M(3) M(4) M(5) M(6) M(7) M(8) M(9) M(10) M(11) \
    M(12) M(13) M(14) M(15) M(16) M(17) M(18) M(19) M(20) M(21) M(22) M(23) \
    M(24) M(25) M(26) M(27) M(28) M(29) M(30) M(31)

// butterfly pair lists per k-bit
#define P4(M) M(A0,A16) M(A1,A17) M(A2,A18) M(A3,A19) M(A4,A20) M(A5,A21) M(A6,A22) M(A7,A23) \
              M(A8,A24) M(A9,A25) M(A10,A26) M(A11,A27) M(A12,A28) M(A13,A29) M(A14,A30) M(A15,A31)
#define P3(M) M(A0,A8) M(A1,A9) M(A2,A10) M(A3,A11) M(A4,A12) M(A5,A13) M(A6,A14) M(A7,A15) \
              M(A16,A24) M(A17,A25) M(A18,A26) M(A19,A27) M(A20,A28) M(A21,A29) M(A22,A30) M(A23,A31)
#define P2(M) M(A0,A4) M(A1,A5) M(A2,A6) M(A3,A7) M(A8,A12) M(A9,A13) M(A10,A14) M(A11,A15) \
              M(A16,A20) M(A17,A21) M(A18,A22) M(A19,A23) M(A24,A28) M(A25,A29) M(A26,A30) M(A27,A31)
#define P1(M) M(A0,A2) M(A1,A3) M(A4,A6) M(A5,A7) M(A8,A10) M(A9,A11) M(A12,A14) M(A13,A15) \
              M(A16,A18) M(A17,A19) M(A20,A22) M(A21,A23) M(A24,A26) M(A25,A27) M(A28,A30) M(A29,A31)
#define P0(M) M(A0,A1) M(A2,A3) M(A4,A5) M(A6,A7) M(A8,A9) M(A10,A11) M(A12,A13) M(A14,A15) \
              M(A16,A17) M(A18,A19) M(A20,A21) M(A22,A23) M(A24,A25) M(A26,A27) M(A28,A29) M(A30,A31)

// 5 gates on k-bits 4..0 = wires W0..W0+4; 32 amps/thread, affine padded addrs.
template<int LO, int W0>
__device__ __forceinline__ void rot_pass5(float2* st_, const float4* G4, int t)
{
    const int base = ((t >> LO) << (LO + 5)) | (t & ((1 << LO) - 1));
    float2* pA = st_ + (base + ((base >> 6) << 1));
#define OFF(k) ((((k)) << LO) + (((((k)) << LO) >> 6) << 1))
    float2* pB = pA + OFF(16);
#define ADR(k) ((k) < 16 ? (pA + OFF(k)) : (pB + OFF((k) - 16)))
#define DECL(k) v2f A##k;
    FE32(DECL)
#undef DECL
#define LD(k) A##k = *(const v2f*)ADR(k);
    FE32(LD)
#undef LD
    { GSTAGE(W0+0) P4(CBFA) }
    { GSTAGE(W0+1) P3(CBFA) }
    { GSTAGE(W0+2) P2(CBFA) }
    { GSTAGE(W0+3) P1(CBFA) }
    { GSTAGE(W0+4) P0(CBFA) }
#define ST(k) *(v2f*)ADR(k) = A##k;
    FE32(ST)
#undef ST
#undef ADR
#undef OFF
}

// contiguous 32-amp load (b128) + gates on wires 10..13 (k-bits 3..0)
#define LOW_LOAD_GATES \
    const float4* lp = (const float4*)(st_ + (32 * t + ((t >> 1) << 1))); \
    const float4 q0 = lp[0],  q1 = lp[1],  q2 = lp[2],  q3 = lp[3], \
                 q4 = lp[4],  q5 = lp[5],  q6 = lp[6],  q7 = lp[7], \
                 q8 = lp[8],  q9 = lp[9],  q10 = lp[10], q11 = lp[11], \
                 q12 = lp[12], q13 = lp[13], q14 = lp[14], q15 = lp[15]; \
    v2f A0  = (v2f){q0.x,q0.y},  A1  = (v2f){q0.z,q0.w}, \
        A2  = (v2f){q1.x,q1.y},  A3  = (v2f){q1.z,q1.w}, \
        A4  = (v2f){q2.x,q2.y},  A5  = (v2f){q2.z,q2.w}, \
        A6  = (v2f){q3.x,q3.y},  A7  = (v2f){q3.z,q3.w}, \
        A8  = (v2f){q4.x,q4.y},  A9  = (v2f){q4.z,q4.w}, \
        A10 = (v2f){q5.x,q5.y},  A11 = (v2f){q5.z,q5.w}, \
        A12 = (v2f){q6.x,q6.y},  A13 = (v2f){q6.z,q6.w}, \
        A14 = (v2f){q7.x,q7.y},  A15 = (v2f){q7.z,q7.w}, \
        A16 = (v2f){q8.x,q8.y},  A17 = (v2f){q8.z,q8.w}, \
        A18 = (v2f){q9.x,q9.y},  A19 = (v2f){q9.z,q9.w}, \
        A20 = (v2f){q10.x,q10.y}, A21 = (v2f){q10.z,q10.w}, \
        A22 = (v2f){q11.x,q11.y}, A23 = (v2f){q11.z,q11.w}, \
        A24 = (v2f){q12.x,q12.y}, A25 = (v2f){q12.z,q12.w}, \
        A26 = (v2f){q13.x,q13.y}, A27 = (v2f){q13.z,q13.w}, \
        A28 = (v2f){q14.x,q14.y}, A29 = (v2f){q14.z,q14.w}, \
        A30 = (v2f){q15.x,q15.y}, A31 = (v2f){q15.z,q15.w}; \
    { GSTAGE(10) P3(CBFA) } \
    { GSTAGE(11) P2(CBFA) } \
    { GSTAGE(12) P1(CBFA) } \
    { GSTAGE(13) P0(CBFA) }

// wires 10..13 + ring permutation folded into scatter (full XOR + SLOT)
template<int RI>
__device__ __forceinline__ void rot_low_ring5(float2* st_, const float4* G4, int t,
                                              const unsigned* lA, const unsigned* lB)
{
    LOW_LOAD_GATES
    const unsigned fb = lA[t & 31] ^ lB[t >> 5];      // image of (t<<5), any bits
    __syncthreads();                                  // all reads done before scatter
#define SC(k) { const unsigned ix = fb ^ RC.flow[RI][(k)]; \
    st_[ix + ((ix >> 6) << 1)] = make_float2(A##k.x, A##k.y); }
    FE32(SC)
#undef SC
}

// final layer: wires 10..13 + ring(RI=1) + <Z> measurement, no writeback
__device__ __forceinline__ float rot_low_meas5(float2* st_, const float4* G4, int t,
                                               const unsigned* lA, const unsigned* lB,
                                               const float* s_hw)
{
    LOW_LOAD_GATES
    const unsigned fb = lA[t & 31] ^ lB[t >> 5];
#define SGV(b) ((((fb >> b) & 1u) ? -1.f : 1.f) * s_hw[13 - (b)])
    const float sg0 = SGV(0),  sg1 = SGV(1),  sg2 = SGV(2),  sg3 = SGV(3),
                sg4 = SGV(4),  sg5 = SGV(5),  sg6 = SGV(6),  sg7 = SGV(7),
                sg8 = SGV(8),  sg9 = SGV(9),  sg10 = SGV(10), sg11 = SGV(11),
                sg12 = SGV(12), sg13 = SGV(13);
#undef SGV
    const float chiS = ((sg0 + sg1) + (sg2 + sg3)) + ((sg4 + sg5) + (sg6 + sg7))
                     + ((sg8 + sg9) + (sg10 + sg11)) + (sg12 + sg13);
#define SUBSUM(F) ( ((F)&1u?sg0:0.f) + ((F)&2u?sg1:0.f) + ((F)&4u?sg2:0.f) + ((F)&8u?sg3:0.f) \
                  + ((F)&16u?sg4:0.f) + ((F)&32u?sg5:0.f) + ((F)&64u?sg6:0.f) + ((F)&128u?sg7:0.f) \
                  + ((F)&256u?sg8:0.f) + ((F)&512u?sg9:0.f) + ((F)&1024u?sg10:0.f) + ((F)&2048u?sg11:0.f) \
                  + ((F)&4096u?sg12:0.f) + ((F)&8192u?sg13:0.f) )
    float acc = 0.f;
#define MEASK(k) { const float p2 = fmaf(A##k.x, A##k.x, A##k.y * A##k.y); \
    acc = fmaf(p2, chiS - 2.f * SUBSUM(RC.flow[1][(k)]), acc); }
    FE32(MEASK)
#undef MEASK
#undef SUBSUM
    return acc;
}

__global__ __launch_bounds__(NTHREADS, 2)
void qsim(const float* __restrict__ sb, const float* __restrict__ pr,
          const float* __restrict__ hw, const float* __restrict__ hb,
          float* __restrict__ out)
{
    __shared__ __align__(16) float2 st[STATE_SLOTS];   // 135,168 B
    __shared__ __align__(16) float4 rotc[2][NW * 4];   // gate consts (R5 format)
    __shared__ unsigned lutA[2][32], lutB[2][16];      // fb LUTs: i bits 5..9 / 10..13
    __shared__ float2 low_tab[32];                     // layer0 product over wires 9..13
    __shared__ float s_hw[NW];
    __shared__ float s_red[NTHREADS / 64];
    __shared__ unsigned s_bmask;

    const int bid = blockIdx.x;
    const int t = threadIdx.x;

    // ---- setup ----
    if (t < 28) {
        int l = t / NW, w = t % NW;
        const float* p = pr + bid * 84 + l * 42 + w * 3;
        float phi = p[0], th = p[1], om = p[2];
        float s, cth;  __sincosf(0.5f * th, &s, &cth);
        float sa, ca, sd, cd;
        __sincosf(0.5f * (phi + om), &sa, &ca);
        __sincosf(0.5f * (phi - om), &sd, &cd);
        const float u00x = ca * cth, u00y = -sa * cth;
        const float u01x = -cd * s,  u01y = -sd * s;
        const float u10x = cd * s,   u10y = -sd * s;
        const float u11x = ca * cth, u11y = sa * cth;
        rotc[l][w*4+0] = make_float4(u00x, u00y, -u00y, u00y);   // {re, im, -im, +im}
        rotc[l][w*4+1] = make_float4(u01x, u01y, -u01y, u01y);
        rotc[l][w*4+2] = make_float4(u10x, u10y, -u10y, u10y);
        rotc[l][w*4+3] = make_float4(u11x, u11y, -u11y, u11y);
    }
    if (t >= 64 && t < 128) {                   // lutA: i bits 5..9 from t bits 0..4
        int j = t - 64, ri = j >> 5, m = j & 31;
        unsigned x = 0;
        for (int b = 0; b < 5; ++b) if ((m >> b) & 1) x ^= RC.col[ri][5 + b];
        lutA[ri][m] = x;
    }
    if (t >= 128 && t < 160) {                  // lutB: i bits 10..13 from t bits 5..8
        int j = t - 128, ri = j >> 4, m = j & 15;
        unsigned x = 0;
        for (int b = 0; b < 4; ++b) if ((m >> b) & 1) x ^= RC.col[ri][10 + b];
        lutB[ri][m] = x;
    }
    if (t >= 160 && t < 174) s_hw[t - 160] = hw[t - 160];
    if (t == 192) {
        const float* row = sb + (size_t)bid * (NSTATE * 2);
        unsigned m = 0;
        for (int w = 0; w < NW; ++w) m |= (row[w] < 0.0f ? 1u : 0u) << (13 - w);
        s_bmask = m;
    }
    __syncthreads();
    if (t < 32) {                               // low_tab[k]: wires 9..13 (i bits 4..0)
        const unsigned bm = s_bmask;
        float2 v = make_float2(1.f, 0.f);
#pragma unroll
        for (int b = 0; b < 5; ++b) {
            int w = 13 - b, kb = (t >> b) & 1, cb = (bm >> b) & 1;
            float4 e = rotc[0][w*4 + kb*2 + cb];
            v = cmul(v, make_float2(e.x, e.y));
        }
        low_tab[t] = v;
    }
    __syncthreads();

    // ---- init: layer 0 on |bm> (product state), ring r=1 folded ----
    {
        const unsigned bm = s_bmask;
        float2 ph = make_float2(1.f, 0.f);
#pragma unroll
        for (int w = 0; w < 9; ++w) {           // wires 0..8 from t bits 8..0
            int v = (t >> (8 - w)) & 1;
            int bw = (bm >> (13 - w)) & 1;
            float4 e = rotc[0][w*4 + v*2 + bw];
            ph = cmul(ph, make_float2(e.x, e.y));
        }
        const unsigned fb = lutA[0][t & 31] ^ lutB[0][t >> 5];
#define INITK(k) { const unsigned ix = fb ^ RC.flow[0][(k)]; \
    const float2 lt = low_tab[(k)]; \
    st[ix + ((ix >> 6) << 1)] = cmul(ph, lt); }
        FE32(INITK)
#undef INITK
    }
    __syncthreads();

    // ---- reps 0..3: layers (1,0,1,0), 3 passes each, trailing ring folded ----
#pragma unroll 1
    for (int rep = 0; rep < 4; ++rep) {
        const int l = (rep & 1) ? 0 : 1;
        const float4* G4 = &rotc[l][0];
        rot_pass5<9, 0>(st, G4, t); __syncthreads();   // wires 0..4
        rot_pass5<4, 5>(st, G4, t); __syncthreads();   // wires 5..9
        if (l) rot_low_ring5<1>(st, G4, t, lutA[1], lutB[1]);
        else   rot_low_ring5<0>(st, G4, t, lutA[0], lutB[0]);
        __syncthreads();
    }
    // ---- final: layer 1, ring r=2 + measurement folded ----
    rot_pass5<9, 0>(st, &rotc[1][0], t); __syncthreads();
    rot_pass5<4, 5>(st, &rotc[1][0], t); __syncthreads();
    float acc = rot_low_meas5(st, &rotc[1][0], t, lutA[1], lutB[1], s_hw);

    for (int off = 32; off > 0; off >>= 1) acc += __shfl_down(acc, off);
    if ((t & 63) == 0) s_red[t >> 6] = acc;
    __syncthreads();
    if (t == 0) {
        float tot = 0.f;
#pragma unroll
        for (int i = 0; i < NTHREADS / 64; ++i) tot += s_red[i];
        out[bid] = tot + hb[0];
    }
}

extern "C" void kernel_launch(void* const* d_in, const int* in_sizes, int n_in,
                              void* d_out, int out_size, void* d_ws, size_t ws_size,
                              hipStream_t stream)
{
    const float* sb = (const float*)d_in[0];   // state_batch (B, 2^14, 2) f32
    const float* pr = (const float*)d_in[1];   // params (B, 84) f32
    const float* hw = (const float*)d_in[2];   // head_w (1, 14) f32
    const float* hb = (const float*)d_in[3];   // head_b (1,) f32
    float* out = (float*)d_out;                // (B,) f32
    const int B = in_sizes[1] / 84;            // 512
    qsim<<<B, NTHREADS, 0, stream>>>(sb, pr, hw, hb, out);
}